// Round 8
// baseline (431.704 us; speedup 1.0000x reference)
//
#include <hip/hip_runtime.h>
#include <hip/hip_bf16.h>

#define NN 50000
#define NE 800000
#define SCAN_BS 1024
#define SCAN_NB ((NN + SCAN_BS - 1) / SCAN_BS)   // 49
#define EB ((NE + 255) / 256)                    // 3125 edge blocks
#define GB ((NN + 63) / 64)                      // 782 gemm blocks
#define RB ((NN + 1 + 255) / 256)                // 196 row blocks

typedef __attribute__((ext_vector_type(8))) __bf16 bf16x8;
typedef __attribute__((ext_vector_type(4))) float float4v;

__device__ __forceinline__ unsigned pack_bf2(float lo, float hi) {
    union { __bf16 b; unsigned short u; } a, c;
    a.b = (__bf16)lo; c.b = (__bf16)hi;
    return (unsigned)a.u | ((unsigned)c.u << 16);
}
__device__ __forceinline__ float2 unpack_bf2(unsigned v) {
    union { unsigned short u; __bf16 b; } lo, hi;
    lo.u = (unsigned short)(v & 0xffff); hi.u = (unsigned short)(v >> 16);
    return make_float2((float)lo.b, (float)hi.b);
}

// ================= fused prep: hist (edges) + 3x convert_w (grid-partitioned) =================
// Wt PRE-PADDED in 64-k chunks: [NC][320][72] bf16 (row stride 144 B).
// Rows 0..127 = Ws cols, 128..255 = Wd cols, 256..319 = Wl cols. Pad cols 64..71 = 0.

__device__ __forceinline__ void convert_w_part(const float* __restrict__ Ws,
                                               const float* __restrict__ Wd,
                                               const float* __restrict__ Wl,
                                               __bf16* __restrict__ Wt, int NC, int i)
{
    if (i >= NC * 23040) return;           // 23040 = 320*72 per chunk
    int chunk = i / 23040, rem = i % 23040;
    int r = rem / 72, c = rem % 72;
    float v = 0.f;
    if (c < 64) {
        int k = chunk * 64 + c;
        if (r < 128)      v = Ws[k * 128 + r];
        else if (r < 256) v = Wd[k * 128 + (r - 128)];
        else              v = Wl[k * 64 + (r - 256)];
    }
    Wt[i] = (__bf16)v;
}

__global__ void __launch_bounds__(256)
prep_kernel(const int* __restrict__ ei, int* __restrict__ deg, int* __restrict__ rank,
            const float* __restrict__ Ws1, const float* __restrict__ Wd1,
            const float* __restrict__ Wl1, __bf16* __restrict__ Wt1,
            const float* __restrict__ Ws2, const float* __restrict__ Wd2,
            const float* __restrict__ Wl2, __bf16* __restrict__ Wt2,
            const float* __restrict__ Ws3, const float* __restrict__ Wd3,
            const float* __restrict__ Wl3, __bf16* __restrict__ Wt3)
{
    int bi = blockIdx.x;
    if (bi < EB) {
        int e = bi * 256 + threadIdx.x;
        if (e < NE) rank[e] = atomicAdd(&deg[ei[NE + e]], 1);
    } else if (bi < EB + 180) {            // layer1: 2 chunks = 46080 elems
        convert_w_part(Ws1, Wd1, Wl1, Wt1, 2, (bi - EB) * 256 + threadIdx.x);
    } else if (bi < EB + 270) {            // layer2: 1 chunk = 23040
        convert_w_part(Ws2, Wd2, Wl2, Wt2, 1, (bi - EB - 180) * 256 + threadIdx.x);
    } else {                               // layer3
        convert_w_part(Ws3, Wd3, Wl3, Wt3, 1, (bi - EB - 270) * 256 + threadIdx.x);
    }
}

// ============================ fused scan (block scan + last-block top scan) ============================

__global__ void __launch_bounds__(SCAN_BS)
scan12_kernel(const int* __restrict__ deg, int* __restrict__ exl,
              int* __restrict__ bsum, int* __restrict__ boff, int* __restrict__ ticket)
{
    __shared__ int sh[SCAN_BS];
    __shared__ int lastFlag;
    int t = threadIdx.x;
    int i = blockIdx.x * SCAN_BS + t;
    int v = (i < NN) ? deg[i] : 0;
    sh[t] = v;
    __syncthreads();
    for (int off = 1; off < SCAN_BS; off <<= 1) {
        int u = (t >= off) ? sh[t - off] : 0;
        __syncthreads();
        sh[t] += u;
        __syncthreads();
    }
    if (i < NN) exl[i] = sh[t] - v;
    if (t == SCAN_BS - 1) {
        bsum[blockIdx.x] = sh[t];
        __threadfence();
        lastFlag = (atomicAdd(ticket, 1) == SCAN_NB - 1);
    }
    __syncthreads();
    if (lastFlag && t < 64) {
        __threadfence();
        int l = t;
        int bv = (l < SCAN_NB) ? bsum[l] : 0;
        int own = bv;
        for (int off = 1; off < 64; off <<= 1) {
            int u = __shfl_up(bv, off);
            if (l >= off) bv += u;
        }
        if (l < SCAN_NB) boff[l] = bv - own;
    }
}

// ============================ MFMA node GEMM (half-tile staging + fused CSR tail) ============================

__device__ __forceinline__ bf16x8 load_af(const __bf16* p) { return *(const bf16x8*)p; }
__device__ __forceinline__ bf16x8 load_af(const float* p) {
    float4 u = *(const float4*)p;
    float4 v = *(const float4*)(p + 4);
    bf16x8 r;
    r[0] = (__bf16)u.x; r[1] = (__bf16)u.y; r[2] = (__bf16)u.z; r[3] = (__bf16)u.w;
    r[4] = (__bf16)v.x; r[5] = (__bf16)v.y; r[6] = (__bf16)v.z; r[7] = (__bf16)v.w;
    return r;
}

template <int K, typename TIN, bool FUSE>
__global__ void __launch_bounds__(256, 4)
mfma_gemm(const TIN* __restrict__ xin, const __bf16* __restrict__ Wt,
          const float* __restrict__ a_s, const float* __restrict__ a_d,
          unsigned* __restrict__ hsb, float* __restrict__ lin,
          float* __restrict__ als, float* __restrict__ ald,
          const int* __restrict__ ei, const int* __restrict__ rank,
          const int* __restrict__ exl, const int* __restrict__ boff,
          int* __restrict__ row, int* __restrict__ csr_src)
{
    const int tid = threadIdx.x;

    if (FUSE && blockIdx.x >= GB) {
        int bi = blockIdx.x - GB;
        if (bi < RB) {
            int i = bi * 256 + tid;
            if (i < NN)       row[i] = exl[i] + boff[i >> 10];
            else if (i == NN) row[i] = NE;
        } else {
            int e = (bi - RB) * 256 + tid;
            if (e < NE) {
                int s = ei[e], d = ei[NE + e];
                csr_src[exl[d] + boff[d >> 10] + rank[e]] = s;
            }
        }
        return;
    }

    constexpr int NPH = (K / 64) * 2;                // 4 phases (K=128), 2 (K=64)
    __shared__ __align__(16) char ldsW[160 * 144];   // 23040 B

    const int lane = tid & 63;
    const int wave = tid >> 6;
    const int l15 = lane & 15, quad = lane >> 4;
    const int n0 = blockIdx.x * 64 + wave * 16;
    const int nA = min(n0 + l15, NN - 1);

    bf16x8 afr[K / 32];
#pragma unroll
    for (int ks = 0; ks < K / 32; ++ks)
        afr[ks] = load_af(xin + (size_t)nA * K + ks * 32 + quad * 8);

    const uint4* gW = (const uint4*)Wt;
    uint4* lw = (uint4*)ldsW;
    uint4 st[6];                                     // 1440 uint4 per phase

#pragma unroll
    for (int i = 0; i < 6; ++i) { int idx = i * 256 + tid; if (idx < 1440) st[i] = gW[idx]; }

    float4v acc[20];
#pragma unroll
    for (int t = 0; t < 20; ++t) acc[t] = (float4v){0.f, 0.f, 0.f, 0.f};

#pragma unroll
    for (int ph = 0; ph < NPH; ++ph) {
        if (ph) __syncthreads();
#pragma unroll
        for (int i = 0; i < 6; ++i) { int idx = i * 256 + tid; if (idx < 1440) lw[idx] = st[i]; }
        __syncthreads();
        if (ph + 1 < NPH) {
            const uint4* gs = gW + (ph + 1) * 1440;
#pragma unroll
            for (int i = 0; i < 6; ++i) { int idx = i * 256 + tid; if (idx < 1440) st[i] = gs[idx]; }
        }
        const int hh = ph & 1, ch = ph >> 1;
#pragma unroll
        for (int ksh = 0; ksh < 2; ++ksh) {
#pragma unroll
            for (int tl = 0; tl < 10; ++tl) {
                bf16x8 bw = *(const bf16x8*)&ldsW[(tl * 16 + l15) * 144 + (ksh * 4 + quad) * 16];
                acc[hh * 10 + tl] =
                    __builtin_amdgcn_mfma_f32_16x16x32_bf16(bw, afr[ch * 2 + ksh], acc[hh * 10 + tl], 0, 0, 0);
            }
        }
    }

    float s0 = 0.f, s1 = 0.f, d0 = 0.f, d1 = 0.f;
#pragma unroll
    for (int t = 0; t < 4; ++t) {
        float4 as0 = *(const float4*)&a_s[t * 16 + quad * 4];
        float4 as1 = *(const float4*)&a_s[64 + t * 16 + quad * 4];
        float4 ad0 = *(const float4*)&a_d[t * 16 + quad * 4];
        float4 ad1 = *(const float4*)&a_d[64 + t * 16 + quad * 4];
        s0 += acc[t][0] * as0.x + acc[t][1] * as0.y + acc[t][2] * as0.z + acc[t][3] * as0.w;
        s1 += acc[t + 4][0] * as1.x + acc[t + 4][1] * as1.y + acc[t + 4][2] * as1.z + acc[t + 4][3] * as1.w;
        d0 += acc[t + 8][0] * ad0.x + acc[t + 8][1] * ad0.y + acc[t + 8][2] * ad0.z + acc[t + 8][3] * ad0.w;
        d1 += acc[t + 12][0] * ad1.x + acc[t + 12][1] * ad1.y + acc[t + 12][2] * ad1.z + acc[t + 12][3] * ad1.w;
    }
    s0 += __shfl_xor(s0, 16); s0 += __shfl_xor(s0, 32);
    s1 += __shfl_xor(s1, 16); s1 += __shfl_xor(s1, 32);
    d0 += __shfl_xor(d0, 16); d0 += __shfl_xor(d0, 32);
    d1 += __shfl_xor(d1, 16); d1 += __shfl_xor(d1, 32);

    int n = n0 + l15;
    if (n < NN) {
#pragma unroll
        for (int t = 0; t < 4; ++t) {
            uint4 u;
            u.x = pack_bf2(acc[t][0], acc[t + 4][0]);
            u.y = pack_bf2(acc[t][1], acc[t + 4][1]);
            u.z = pack_bf2(acc[t][2], acc[t + 4][2]);
            u.w = pack_bf2(acc[t][3], acc[t + 4][3]);
            *(uint4*)&hsb[(size_t)n * 64 + t * 16 + quad * 4] = u;
            *(float4*)&lin[(size_t)n * 64 + t * 16 + quad * 4] =
                make_float4(acc[16 + t][0], acc[16 + t][1], acc[16 + t][2], acc[16 + t][3]);
        }
        if (quad == 0) *(float2*)&als[(size_t)n * 2] = make_float2(s0, s1);
        if (quad == 1) *(float2*)&ald[(size_t)n * 2] = make_float2(d0, d1);
    }
}

// ============================ aggregate (R29: software-pipelined gather) ============================
// The agg loop is a 2-level pointer chase: csr_src[p] -> {als[s], hsb[s]}.
// R23 exposed the csr+als+exp latency every iteration. R29 rotates the
// index/weight stage one iteration ahead: while iter i's 4 hsb gathers + FMAs
// run, iter i+1's csr_src loads, als loads and leaky-relu+exp execute.
// VGPR ~75-80 -> launch_bounds (256,6) = 24 waves/CU (was 32); chains/CU
// 24x8=192 vs 32x4=128.

__device__ __forceinline__ float2 edge_w(const float* __restrict__ als, int s,
                                         float ad0, float ad1)
{
    float2 al = *(const float2*)&als[s * 2];
    float e0 = al.x + ad0; e0 = (e0 >= 0.f) ? e0 : 0.2f * e0;
    float e1 = al.y + ad1; e1 = (e1 >= 0.f) ? e1 : 0.2f * e1;
    return make_float2(__expf(e0), __expf(e1));
}

__device__ __forceinline__ void store_q(float* p, float v0, float v1, float v2, float v3) {
    *(float4*)p = make_float4(v0, v1, v2, v3);
}
__device__ __forceinline__ void store_q(__bf16* p, float v0, float v1, float v2, float v3) {
    *(uint2*)p = make_uint2(pack_bf2(v0, v1), pack_bf2(v2, v3));
}

template <typename TO>
__global__ void __launch_bounds__(256, 6)
gat_aggregate(const int* __restrict__ row, const int* __restrict__ csr_src,
              const float* __restrict__ als, const float* __restrict__ ald,
              const unsigned* __restrict__ hsb, const float* __restrict__ lin,
              const float* __restrict__ b, const float* __restrict__ bl,
              TO* __restrict__ out)
{
    int w = (blockIdx.x * 256 + threadIdx.x) >> 6;
    int lane = threadIdx.x & 63;
    int q = lane >> 4;
    int l15 = lane & 15;
    if (w >= NN) return;
    int p0 = row[w], p1 = row[w + 1];
    float ad0 = ald[w * 2 + 0];
    float ad1 = ald[w * 2 + 1];

    float a0[4] = {0.f, 0.f, 0.f, 0.f};
    float a1[4] = {0.f, 0.f, 0.f, 0.f};
    float den0 = 0.f, den1 = 0.f;

    int pIt = p0 + q;
    int sC[4]; float2 eC[4];
#pragma unroll
    for (int j = 0; j < 4; ++j) { sC[j] = 0; eC[j] = make_float2(0.f, 0.f); }

    if (pIt < p1) {
#pragma unroll
        for (int j = 0; j < 4; ++j) {
            int pp = pIt + 4 * j;
            bool lv = (pp < p1);
            int s = csr_src[lv ? pp : p0];
            sC[j] = s;
            float2 e = edge_w(als, s, ad0, ad1);
            eC[j] = lv ? e : make_float2(0.f, 0.f);
        }
    }

    while (pIt < p1) {
        int pN = pIt + 16;
        int sN[4]; float2 eN[4];
        bool more = (pN < p1);
        if (more) {                      // prefetch next iteration's indices + weights
#pragma unroll
            for (int j = 0; j < 4; ++j) {
                int pp = pN + 4 * j;
                bool lv = (pp < p1);
                int s = csr_src[lv ? pp : p0];
                sN[j] = s;
                float2 e = edge_w(als, s, ad0, ad1);
                eN[j] = lv ? e : make_float2(0.f, 0.f);
            }
        }
        // current iteration's gathers + accumulation (s known since last iter)
#pragma unroll
        for (int j = 0; j < 4; ++j) {
            uint4 g = *(const uint4*)&hsb[(size_t)sC[j] * 64 + 4 * l15];
            float2 e = eC[j];
            den0 += e.x; den1 += e.y;
            float2 h;
            h = unpack_bf2(g.x); a0[0] += e.x * h.x; a1[0] += e.y * h.y;
            h = unpack_bf2(g.y); a0[1] += e.x * h.x; a1[1] += e.y * h.y;
            h = unpack_bf2(g.z); a0[2] += e.x * h.x; a1[2] += e.y * h.y;
            h = unpack_bf2(g.w); a0[3] += e.x * h.x; a1[3] += e.y * h.y;
        }
        if (more) {
#pragma unroll
            for (int j = 0; j < 4; ++j) { sC[j] = sN[j]; eC[j] = eN[j]; }
        }
        pIt = pN;
    }

#pragma unroll
    for (int i = 0; i < 4; ++i) {
        a0[i] += __shfl_xor(a0[i], 16); a0[i] += __shfl_xor(a0[i], 32);
        a1[i] += __shfl_xor(a1[i], 16); a1[i] += __shfl_xor(a1[i], 32);
    }
    den0 += __shfl_xor(den0, 16); den0 += __shfl_xor(den0, 32);
    den1 += __shfl_xor(den1, 16); den1 += __shfl_xor(den1, 32);

    if (q == 0) {
        int c0 = 4 * l15;
        float r0 = 1.f / (den0 + 1e-16f);
        float r1 = 1.f / (den1 + 1e-16f);
        float4 lv = *(const float4*)&lin[(size_t)w * 64 + c0];
        float v0 = 0.5f * (a0[0] * r0 + a1[0] * r1) + b[c0 + 0] + bl[c0 + 0] + lv.x;
        float v1 = 0.5f * (a0[1] * r0 + a1[1] * r1) + b[c0 + 1] + bl[c0 + 1] + lv.y;
        float v2 = 0.5f * (a0[2] * r0 + a1[2] * r1) + b[c0 + 2] + bl[c0 + 2] + lv.z;
        float v3 = 0.5f * (a0[3] * r0 + a1[3] * r1) + b[c0 + 3] + bl[c0 + 3] + lv.w;
        store_q(&out[(size_t)w * 64 + c0],
                fmaxf(v0, 0.f), fmaxf(v1, 0.f), fmaxf(v2, 0.f), fmaxf(v3, 0.f));
    }
}

// ============================ launch ============================

extern "C" void kernel_launch(void* const* d_in, const int* in_sizes, int n_in,
                              void* d_out, int out_size, void* d_ws, size_t ws_size,
                              hipStream_t stream)
{
    const float* x  = (const float*)d_in[0];
    const int*   ei = (const int*)d_in[1];
    const float* Ws[3]; const float* Wd[3]; const float* As[3]; const float* Ad[3];
    const float* Bb[3]; const float* Wl[3]; const float* Bl[3];
    for (int l = 0; l < 3; ++l) {
        int base = 2 + 7 * l;
        Ws[l] = (const float*)d_in[base + 0];
        Wd[l] = (const float*)d_in[base + 1];
        As[l] = (const float*)d_in[base + 2];
        Ad[l] = (const float*)d_in[base + 3];
        Bb[l] = (const float*)d_in[base + 4];
        Wl[l] = (const float*)d_in[base + 5];
        Bl[l] = (const float*)d_in[base + 6];
    }

    float* ws = (float*)d_ws;
    unsigned* hsb = (unsigned*)ws;                   // NN*64 packed bf16x2
    float* lin  = (float*)(hsb + (size_t)NN * 64);   // NN*64 f32
    float* als  = lin + (size_t)NN * 64;             // NN*2
    float* ald  = als + (size_t)NN * 2;              // NN*2
    __bf16* hb  = (__bf16*)(ald + (size_t)NN * 2);   // NN*64 bf16
    __bf16* Wt1 = hb + (size_t)NN * 64;              // 2*320*72 padded
    __bf16* Wt2 = Wt1 + 2 * 320 * 72;                // 320*72
    __bf16* Wt3 = Wt2 + 320 * 72;                    // 320*72
    int* row     = (int*)(Wt3 + 320 * 72);           // NN+1
    int* deg     = row + (NN + 1);                   // NN
    int* ticket  = deg + NN;                         // 1 (zeroed with deg)
    int* rank    = ticket + 1;                       // NE
    int* exl     = rank + NE;                        // NN
    int* bsum    = exl + NN;                         // SCAN_NB
    int* boff    = bsum + SCAN_NB;                   // SCAN_NB
    int* csr_src = boff + SCAN_NB;                   // NE

    const int WB = (NN * 64 + 255) / 256;

    // --- CSR front pipeline: memset -> prep(hist+convert) -> scan12 ---
    hipMemsetAsync(deg, 0, sizeof(int) * (NN + 1), stream);   // deg + ticket
    prep_kernel<<<EB + 360, 256, 0, stream>>>(ei, deg, rank,
        Ws[0], Wd[0], Wl[0], Wt1,
        Ws[1], Wd[1], Wl[1], Wt2,
        Ws[2], Wd[2], Wl[2], Wt3);
    scan12_kernel<<<SCAN_NB, SCAN_BS, 0, stream>>>(deg, exl, bsum, boff, ticket);

    for (int l = 0; l < 3; ++l) {
        if (l == 0) {
            // layer-1 GEMM + fused CSR finish (row + scatter hidden in tail blocks)
            mfma_gemm<128, float, true><<<GB + RB + EB, 256, 0, stream>>>(
                x, Wt1, As[0], Ad[0], hsb, lin, als, ald,
                ei, rank, exl, boff, row, csr_src);
        } else {
            const __bf16* wt = (l == 1) ? Wt2 : Wt3;
            mfma_gemm<64, __bf16, false><<<GB, 256, 0, stream>>>(
                hb, wt, As[l], Ad[l], hsb, lin, als, ald,
                nullptr, nullptr, nullptr, nullptr, nullptr, nullptr);
        }
        if (l == 2) {
            gat_aggregate<float><<<WB, 256, 0, stream>>>(
                row, csr_src, als, ald, hsb, lin, Bb[l], Bl[l], (float*)d_out);
        } else {
            gat_aggregate<__bf16><<<WB, 256, 0, stream>>>(
                row, csr_src, als, ald, hsb, lin, Bb[l], Bl[l], hb);
        }
    }
}

// Round 9
// 353.650 us; speedup vs baseline: 1.2207x; 1.2207x over previous
//
#include <hip/hip_runtime.h>
#include <hip/hip_bf16.h>

#define NN 50000
#define NE 800000
#define SCAN_BS 1024
#define SCAN_NB ((NN + SCAN_BS - 1) / SCAN_BS)   // 49
#define EB ((NE + 255) / 256)                    // 3125 edge blocks
#define GB ((NN + 63) / 64)                      // 782 gemm blocks
#define RB ((NN + 1 + 255) / 256)                // 196 row blocks

typedef __attribute__((ext_vector_type(8))) __bf16 bf16x8;
typedef __attribute__((ext_vector_type(4))) float float4v;

__device__ __forceinline__ unsigned pack_bf2(float lo, float hi) {
    union { __bf16 b; unsigned short u; } a, c;
    a.b = (__bf16)lo; c.b = (__bf16)hi;
    return (unsigned)a.u | ((unsigned)c.u << 16);
}
__device__ __forceinline__ float2 unpack_bf2(unsigned v) {
    union { unsigned short u; __bf16 b; } lo, hi;
    lo.u = (unsigned short)(v & 0xffff); hi.u = (unsigned short)(v >> 16);
    return make_float2((float)lo.b, (float)hi.b);
}

// ================= fused prep: hist (edges) + 3x convert_w (grid-partitioned) =================
// Wt PRE-PADDED in 64-k chunks: [NC][320][72] bf16 (row stride 144 B).
// Rows 0..127 = Ws cols, 128..255 = Wd cols, 256..319 = Wl cols. Pad cols 64..71 = 0.

__device__ __forceinline__ void convert_w_part(const float* __restrict__ Ws,
                                               const float* __restrict__ Wd,
                                               const float* __restrict__ Wl,
                                               __bf16* __restrict__ Wt, int NC, int i)
{
    if (i >= NC * 23040) return;           // 23040 = 320*72 per chunk
    int chunk = i / 23040, rem = i % 23040;
    int r = rem / 72, c = rem % 72;
    float v = 0.f;
    if (c < 64) {
        int k = chunk * 64 + c;
        if (r < 128)      v = Ws[k * 128 + r];
        else if (r < 256) v = Wd[k * 128 + (r - 128)];
        else              v = Wl[k * 64 + (r - 256)];
    }
    Wt[i] = (__bf16)v;
}

__global__ void __launch_bounds__(256)
prep_kernel(const int* __restrict__ ei, int* __restrict__ deg, int* __restrict__ rank,
            const float* __restrict__ Ws1, const float* __restrict__ Wd1,
            const float* __restrict__ Wl1, __bf16* __restrict__ Wt1,
            const float* __restrict__ Ws2, const float* __restrict__ Wd2,
            const float* __restrict__ Wl2, __bf16* __restrict__ Wt2,
            const float* __restrict__ Ws3, const float* __restrict__ Wd3,
            const float* __restrict__ Wl3, __bf16* __restrict__ Wt3)
{
    int bi = blockIdx.x;
    if (bi < EB) {
        int e = bi * 256 + threadIdx.x;
        if (e < NE) rank[e] = atomicAdd(&deg[ei[NE + e]], 1);
    } else if (bi < EB + 180) {            // layer1: 2 chunks = 46080 elems
        convert_w_part(Ws1, Wd1, Wl1, Wt1, 2, (bi - EB) * 256 + threadIdx.x);
    } else if (bi < EB + 270) {            // layer2: 1 chunk = 23040
        convert_w_part(Ws2, Wd2, Wl2, Wt2, 1, (bi - EB - 180) * 256 + threadIdx.x);
    } else {                               // layer3
        convert_w_part(Ws3, Wd3, Wl3, Wt3, 1, (bi - EB - 270) * 256 + threadIdx.x);
    }
}

// ============================ fused scan (block scan + last-block top scan) ============================

__global__ void __launch_bounds__(SCAN_BS)
scan12_kernel(const int* __restrict__ deg, int* __restrict__ exl,
              int* __restrict__ bsum, int* __restrict__ boff, int* __restrict__ ticket)
{
    __shared__ int sh[SCAN_BS];
    __shared__ int lastFlag;
    int t = threadIdx.x;
    int i = blockIdx.x * SCAN_BS + t;
    int v = (i < NN) ? deg[i] : 0;
    sh[t] = v;
    __syncthreads();
    for (int off = 1; off < SCAN_BS; off <<= 1) {
        int u = (t >= off) ? sh[t - off] : 0;
        __syncthreads();
        sh[t] += u;
        __syncthreads();
    }
    if (i < NN) exl[i] = sh[t] - v;
    if (t == SCAN_BS - 1) {
        bsum[blockIdx.x] = sh[t];
        __threadfence();
        lastFlag = (atomicAdd(ticket, 1) == SCAN_NB - 1);
    }
    __syncthreads();
    if (lastFlag && t < 64) {
        __threadfence();
        int l = t;
        int bv = (l < SCAN_NB) ? bsum[l] : 0;
        int own = bv;
        for (int off = 1; off < 64; off <<= 1) {
            int u = __shfl_up(bv, off);
            if (l >= off) bv += u;
        }
        if (l < SCAN_NB) boff[l] = bv - own;
    }
}

// ============================ MFMA node GEMM (half-tile staging + fused CSR tail) ============================

__device__ __forceinline__ bf16x8 load_af(const __bf16* p) { return *(const bf16x8*)p; }
__device__ __forceinline__ bf16x8 load_af(const float* p) {
    float4 u = *(const float4*)p;
    float4 v = *(const float4*)(p + 4);
    bf16x8 r;
    r[0] = (__bf16)u.x; r[1] = (__bf16)u.y; r[2] = (__bf16)u.z; r[3] = (__bf16)u.w;
    r[4] = (__bf16)v.x; r[5] = (__bf16)v.y; r[6] = (__bf16)v.z; r[7] = (__bf16)v.w;
    return r;
}

template <int K, typename TIN, bool FUSE>
__global__ void __launch_bounds__(256, 4)
mfma_gemm(const TIN* __restrict__ xin, const __bf16* __restrict__ Wt,
          const float* __restrict__ a_s, const float* __restrict__ a_d,
          unsigned* __restrict__ hsb, float* __restrict__ lin,
          float* __restrict__ als, float* __restrict__ ald,
          const int* __restrict__ ei, const int* __restrict__ rank,
          const int* __restrict__ exl, const int* __restrict__ boff,
          int* __restrict__ row, int* __restrict__ csr_src)
{
    const int tid = threadIdx.x;

    if (FUSE && blockIdx.x >= GB) {
        int bi = blockIdx.x - GB;
        if (bi < RB) {
            int i = bi * 256 + tid;
            if (i < NN)       row[i] = exl[i] + boff[i >> 10];
            else if (i == NN) row[i] = NE;
        } else {
            int e = (bi - RB) * 256 + tid;
            if (e < NE) {
                int s = ei[e], d = ei[NE + e];
                csr_src[exl[d] + boff[d >> 10] + rank[e]] = s;
            }
        }
        return;
    }

    constexpr int NPH = (K / 64) * 2;                // 4 phases (K=128), 2 (K=64)
    __shared__ __align__(16) char ldsW[160 * 144];   // 23040 B

    const int lane = tid & 63;
    const int wave = tid >> 6;
    const int l15 = lane & 15, quad = lane >> 4;
    const int n0 = blockIdx.x * 64 + wave * 16;
    const int nA = min(n0 + l15, NN - 1);

    bf16x8 afr[K / 32];
#pragma unroll
    for (int ks = 0; ks < K / 32; ++ks)
        afr[ks] = load_af(xin + (size_t)nA * K + ks * 32 + quad * 8);

    const uint4* gW = (const uint4*)Wt;
    uint4* lw = (uint4*)ldsW;
    uint4 st[6];                                     // 1440 uint4 per phase

#pragma unroll
    for (int i = 0; i < 6; ++i) { int idx = i * 256 + tid; if (idx < 1440) st[i] = gW[idx]; }

    float4v acc[20];
#pragma unroll
    for (int t = 0; t < 20; ++t) acc[t] = (float4v){0.f, 0.f, 0.f, 0.f};

#pragma unroll
    for (int ph = 0; ph < NPH; ++ph) {
        if (ph) __syncthreads();
#pragma unroll
        for (int i = 0; i < 6; ++i) { int idx = i * 256 + tid; if (idx < 1440) lw[idx] = st[i]; }
        __syncthreads();
        if (ph + 1 < NPH) {
            const uint4* gs = gW + (ph + 1) * 1440;
#pragma unroll
            for (int i = 0; i < 6; ++i) { int idx = i * 256 + tid; if (idx < 1440) st[i] = gs[idx]; }
        }
        const int hh = ph & 1, ch = ph >> 1;
#pragma unroll
        for (int ksh = 0; ksh < 2; ++ksh) {
#pragma unroll
            for (int tl = 0; tl < 10; ++tl) {
                bf16x8 bw = *(const bf16x8*)&ldsW[(tl * 16 + l15) * 144 + (ksh * 4 + quad) * 16];
                acc[hh * 10 + tl] =
                    __builtin_amdgcn_mfma_f32_16x16x32_bf16(bw, afr[ch * 2 + ksh], acc[hh * 10 + tl], 0, 0, 0);
            }
        }
    }

    float s0 = 0.f, s1 = 0.f, d0 = 0.f, d1 = 0.f;
#pragma unroll
    for (int t = 0; t < 4; ++t) {
        float4 as0 = *(const float4*)&a_s[t * 16 + quad * 4];
        float4 as1 = *(const float4*)&a_s[64 + t * 16 + quad * 4];
        float4 ad0 = *(const float4*)&a_d[t * 16 + quad * 4];
        float4 ad1 = *(const float4*)&a_d[64 + t * 16 + quad * 4];
        s0 += acc[t][0] * as0.x + acc[t][1] * as0.y + acc[t][2] * as0.z + acc[t][3] * as0.w;
        s1 += acc[t + 4][0] * as1.x + acc[t + 4][1] * as1.y + acc[t + 4][2] * as1.z + acc[t + 4][3] * as1.w;
        d0 += acc[t + 8][0] * ad0.x + acc[t + 8][1] * ad0.y + acc[t + 8][2] * ad0.z + acc[t + 8][3] * ad0.w;
        d1 += acc[t + 12][0] * ad1.x + acc[t + 12][1] * ad1.y + acc[t + 12][2] * ad1.z + acc[t + 12][3] * ad1.w;
    }
    s0 += __shfl_xor(s0, 16); s0 += __shfl_xor(s0, 32);
    s1 += __shfl_xor(s1, 16); s1 += __shfl_xor(s1, 32);
    d0 += __shfl_xor(d0, 16); d0 += __shfl_xor(d0, 32);
    d1 += __shfl_xor(d1, 16); d1 += __shfl_xor(d1, 32);

    int n = n0 + l15;
    if (n < NN) {
#pragma unroll
        for (int t = 0; t < 4; ++t) {
            uint4 u;
            u.x = pack_bf2(acc[t][0], acc[t + 4][0]);
            u.y = pack_bf2(acc[t][1], acc[t + 4][1]);
            u.z = pack_bf2(acc[t][2], acc[t + 4][2]);
            u.w = pack_bf2(acc[t][3], acc[t + 4][3]);
            *(uint4*)&hsb[(size_t)n * 64 + t * 16 + quad * 4] = u;
            *(float4*)&lin[(size_t)n * 64 + t * 16 + quad * 4] =
                make_float4(acc[16 + t][0], acc[16 + t][1], acc[16 + t][2], acc[16 + t][3]);
        }
        if (quad == 0) *(float2*)&als[(size_t)n * 2] = make_float2(s0, s1);
        if (quad == 1) *(float2*)&ald[(size_t)n * 2] = make_float2(d0, d1);
    }
}

// ============================ fused aggregate (predicated 16-edge loop, high occupancy) ============================
// R31 note: this simple form is the fastest measured (R23). R29's 2-deep
// software pipeline REGRESSED it (73.6 us vs <53; same ~283 MB moved at
// 3.85 vs ~5+ TB/s) -- the agg is traffic-bound at near the achievable BW
// ceiling, not chase-latency-bound. Keep (256,8) + simple predicated loop.

__device__ __forceinline__ float2 edge_w(const float* __restrict__ als, int s,
                                         float ad0, float ad1)
{
    float2 al = *(const float2*)&als[s * 2];
    float e0 = al.x + ad0; e0 = (e0 >= 0.f) ? e0 : 0.2f * e0;
    float e1 = al.y + ad1; e1 = (e1 >= 0.f) ? e1 : 0.2f * e1;
    return make_float2(__expf(e0), __expf(e1));
}

__device__ __forceinline__ void store_q(float* p, float v0, float v1, float v2, float v3) {
    *(float4*)p = make_float4(v0, v1, v2, v3);
}
__device__ __forceinline__ void store_q(__bf16* p, float v0, float v1, float v2, float v3) {
    *(uint2*)p = make_uint2(pack_bf2(v0, v1), pack_bf2(v2, v3));
}

template <typename TO>
__global__ void __launch_bounds__(256, 8)
gat_aggregate(const int* __restrict__ row, const int* __restrict__ csr_src,
              const float* __restrict__ als, const float* __restrict__ ald,
              const unsigned* __restrict__ hsb, const float* __restrict__ lin,
              const float* __restrict__ b, const float* __restrict__ bl,
              TO* __restrict__ out)
{
    int w = (blockIdx.x * 256 + threadIdx.x) >> 6;
    int lane = threadIdx.x & 63;
    int q = lane >> 4;
    int l15 = lane & 15;
    if (w >= NN) return;
    int p0 = row[w], p1 = row[w + 1];
    float ad0 = ald[w * 2 + 0];
    float ad1 = ald[w * 2 + 1];

    float a0[4] = {0.f, 0.f, 0.f, 0.f};
    float a1[4] = {0.f, 0.f, 0.f, 0.f};
    float den0 = 0.f, den1 = 0.f;

    for (int p = p0 + q; p < p1; p += 16) {
#pragma unroll
        for (int j = 0; j < 4; ++j) {
            int pp = p + 4 * j;
            bool live = (pp < p1);
            int s = csr_src[live ? pp : p0];
            float2 e = edge_w(als, s, ad0, ad1);
            if (!live) e = make_float2(0.f, 0.f);
            uint4 g = *(const uint4*)&hsb[(size_t)s * 64 + 4 * l15];
            den0 += e.x; den1 += e.y;
            float2 h;
            h = unpack_bf2(g.x); a0[0] += e.x * h.x; a1[0] += e.y * h.y;
            h = unpack_bf2(g.y); a0[1] += e.x * h.x; a1[1] += e.y * h.y;
            h = unpack_bf2(g.z); a0[2] += e.x * h.x; a1[2] += e.y * h.y;
            h = unpack_bf2(g.w); a0[3] += e.x * h.x; a1[3] += e.y * h.y;
        }
    }

#pragma unroll
    for (int i = 0; i < 4; ++i) {
        a0[i] += __shfl_xor(a0[i], 16); a0[i] += __shfl_xor(a0[i], 32);
        a1[i] += __shfl_xor(a1[i], 16); a1[i] += __shfl_xor(a1[i], 32);
    }
    den0 += __shfl_xor(den0, 16); den0 += __shfl_xor(den0, 32);
    den1 += __shfl_xor(den1, 16); den1 += __shfl_xor(den1, 32);

    if (q == 0) {
        int c0 = 4 * l15;
        float r0 = 1.f / (den0 + 1e-16f);
        float r1 = 1.f / (den1 + 1e-16f);
        float4 lv = *(const float4*)&lin[(size_t)w * 64 + c0];
        float v0 = 0.5f * (a0[0] * r0 + a1[0] * r1) + b[c0 + 0] + bl[c0 + 0] + lv.x;
        float v1 = 0.5f * (a0[1] * r0 + a1[1] * r1) + b[c0 + 1] + bl[c0 + 1] + lv.y;
        float v2 = 0.5f * (a0[2] * r0 + a1[2] * r1) + b[c0 + 2] + bl[c0 + 2] + lv.z;
        float v3 = 0.5f * (a0[3] * r0 + a1[3] * r1) + b[c0 + 3] + bl[c0 + 3] + lv.w;
        store_q(&out[(size_t)w * 64 + c0],
                fmaxf(v0, 0.f), fmaxf(v1, 0.f), fmaxf(v2, 0.f), fmaxf(v3, 0.f));
    }
}

// ============================ launch ============================

extern "C" void kernel_launch(void* const* d_in, const int* in_sizes, int n_in,
                              void* d_out, int out_size, void* d_ws, size_t ws_size,
                              hipStream_t stream)
{
    const float* x  = (const float*)d_in[0];
    const int*   ei = (const int*)d_in[1];
    const float* Ws[3]; const float* Wd[3]; const float* As[3]; const float* Ad[3];
    const float* Bb[3]; const float* Wl[3]; const float* Bl[3];
    for (int l = 0; l < 3; ++l) {
        int base = 2 + 7 * l;
        Ws[l] = (const float*)d_in[base + 0];
        Wd[l] = (const float*)d_in[base + 1];
        As[l] = (const float*)d_in[base + 2];
        Ad[l] = (const float*)d_in[base + 3];
        Bb[l] = (const float*)d_in[base + 4];
        Wl[l] = (const float*)d_in[base + 5];
        Bl[l] = (const float*)d_in[base + 6];
    }

    float* ws = (float*)d_ws;
    unsigned* hsb = (unsigned*)ws;                   // NN*64 packed bf16x2
    float* lin  = (float*)(hsb + (size_t)NN * 64);   // NN*64 f32
    float* als  = lin + (size_t)NN * 64;             // NN*2
    float* ald  = als + (size_t)NN * 2;              // NN*2
    __bf16* hb  = (__bf16*)(ald + (size_t)NN * 2);   // NN*64 bf16
    __bf16* Wt1 = hb + (size_t)NN * 64;              // 2*320*72 padded
    __bf16* Wt2 = Wt1 + 2 * 320 * 72;                // 320*72
    __bf16* Wt3 = Wt2 + 320 * 72;                    // 320*72
    int* row     = (int*)(Wt3 + 320 * 72);           // NN+1
    int* deg     = row + (NN + 1);                   // NN
    int* ticket  = deg + NN;                         // 1 (zeroed with deg)
    int* rank    = ticket + 1;                       // NE
    int* exl     = rank + NE;                        // NN
    int* bsum    = exl + NN;                         // SCAN_NB
    int* boff    = bsum + SCAN_NB;                   // SCAN_NB
    int* csr_src = boff + SCAN_NB;                   // NE

    const int WB = (NN * 64 + 255) / 256;

    // --- CSR front pipeline: memset -> prep(hist+convert) -> scan12 ---
    hipMemsetAsync(deg, 0, sizeof(int) * (NN + 1), stream);   // deg + ticket
    prep_kernel<<<EB + 360, 256, 0, stream>>>(ei, deg, rank,
        Ws[0], Wd[0], Wl[0], Wt1,
        Ws[1], Wd[1], Wl[1], Wt2,
        Ws[2], Wd[2], Wl[2], Wt3);
    scan12_kernel<<<SCAN_NB, SCAN_BS, 0, stream>>>(deg, exl, bsum, boff, ticket);

    for (int l = 0; l < 3; ++l) {
        if (l == 0) {
            // layer-1 GEMM + fused CSR finish (row + scatter hidden in tail blocks)
            mfma_gemm<128, float, true><<<GB + RB + EB, 256, 0, stream>>>(
                x, Wt1, As[0], Ad[0], hsb, lin, als, ald,
                ei, rank, exl, boff, row, csr_src);
        } else {
            const __bf16* wt = (l == 1) ? Wt2 : Wt3;
            mfma_gemm<64, __bf16, false><<<GB, 256, 0, stream>>>(
                hb, wt, As[l], Ad[l], hsb, lin, als, ald,
                nullptr, nullptr, nullptr, nullptr, nullptr, nullptr);
        }
        if (l == 2) {
            gat_aggregate<float><<<WB, 256, 0, stream>>>(
                row, csr_src, als, ald, hsb, lin, Bb[l], Bl[l], (float*)d_out);
        } else {
            gat_aggregate<__bf16><<<WB, 256, 0, stream>>>(
                row, csr_src, als, ald, hsb, lin, Bb[l], Bl[l], hb);
        }
    }
}